// Round 1
// 310.442 us; speedup vs baseline: 1.0239x; 1.0239x over previous
//
#include <hip/hip_runtime.h>
#include <hip/hip_bf16.h>

// GroupFC: C[32768,1024] = A[32768,1024] @ W[1024,1024]^T + b[1024], fp32 in/out.
// R4: (1) FUSE the A fp32->bf16 conversion into the GEMM (reg-stage A fp32,
// convert in-register, ds_write_b128 into the XOR-swizzled LDS layout) -- kills
// the 201 MB convert pass and the 67 MB bf16 re-read. W (only 2 MB bf16) keeps
// the cheap pre-convert + global_load_lds path. (2) Bijective XCD-aware grid
// swizzle: bid&7 -> XCD, each XCD owns 32 contiguous M-tiles with n fastest, so
// the 8 blocks sharing an A-tile hit the SAME per-XCD L2 (fixes the 4x A
// over-fetch seen in FETCH_SIZE=265MB vs 69MB ideal). (3) Next-tile A loads are
// issued after the compute-side barrier so HBM latency hides under MFMA (T14).

#define M_DIM 32768
#define N_DIM 1024
#define K_DIM 1024
#define BM 128
#define BN 128
#define BK 64

typedef __attribute__((ext_vector_type(8))) short bf16x8;
typedef __attribute__((ext_vector_type(16))) float f32x16;
typedef __attribute__((ext_vector_type(8))) unsigned short ushort8v;

typedef const __attribute__((address_space(1))) unsigned int* gptr_t;
typedef __attribute__((address_space(3))) unsigned int* lptr_t;

static __device__ __forceinline__ unsigned short f2bf(float x) {
    union { __hip_bfloat16 h; unsigned short u; } cv;
    cv.h = __float2bfloat16(x);  // RNE
    return cv.u;
}

// ---------------- pass 1 (W only, 2 MB): fp32 -> bf16 ----------------
__global__ __launch_bounds__(256) void convert_f32_bf16(
    const float* __restrict__ in, unsigned short* __restrict__ out) {
    const int idx = (blockIdx.x * 256 + threadIdx.x) * 8;
    float4 v0 = *(const float4*)(in + idx);
    float4 v1 = *(const float4*)(in + idx + 4);
    ushort8v o;
    o[0] = f2bf(v0.x); o[1] = f2bf(v0.y); o[2] = f2bf(v0.z); o[3] = f2bf(v0.w);
    o[4] = f2bf(v1.x); o[5] = f2bf(v1.y); o[6] = f2bf(v1.z); o[7] = f2bf(v1.w);
    *(ushort8v*)(out + idx) = o;  // 16B store
}

// ---------------- fused GEMM: A fp32 (cvt in-kernel), W bf16 ----------------
// LDS tile layout (both As, Bs): 128 rows x 8 chunks (chunk = 8 bf16 = 16B);
// global chunk c of row r lives at slot r*8 + (c ^ (r&7)).
// B side: global_load_lds fills slots in lane order, each lane pre-swizzles its
// global source chunk. A side: reg-staged fp32, cvt, ds_write to swizzled slot.
__global__ __launch_bounds__(256, 3) void gemm_fused(
    const float* __restrict__ A,            // [M,K] fp32
    const unsigned short* __restrict__ W,   // [N,K] bf16
    const float* __restrict__ bias,         // [N]
    float* __restrict__ C)                  // [M,N] fp32
{
    __shared__ unsigned short As[BM * BK];  // 16 KB
    __shared__ unsigned short Bs[BN * BK];  // 16 KB

    const int tid  = threadIdx.x;
    const int wave = tid >> 6;
    const int lane = tid & 63;

    // XCD-aware swizzle: 2048 blocks = 256 M-tiles x 8 N-tiles, 8 XCDs.
    // bid%8 -> XCD (dispatch round-robin); each XCD gets M-tiles [xcd*32, xcd*32+32),
    // n varies fastest so the 8 blocks sharing an A-tile are time-adjacent on ONE L2.
    const int bid = blockIdx.x;
    const int xcd = bid & 7;
    const int loc = bid >> 3;                      // 0..255
    const int bm0 = (xcd * 32 + (loc >> 3)) * BM;  // bijective over 256 M-tiles
    const int bn0 = (loc & 7) * BN;

    const int wr   = wave >> 1;        // wave row slab (64)
    const int wc   = wave & 1;         // wave col slab (64)
    const int l31  = lane & 31;
    const int half = lane >> 5;        // 0..1

    f32x16 acc[2][2];
#pragma unroll
    for (int i = 0; i < 2; ++i)
#pragma unroll
        for (int j = 0; j < 2; ++j)
#pragma unroll
            for (int r = 0; r < 16; ++r)
                acc[i][j][r] = 0.f;

    const float* Ag          = A + (size_t)bm0 * K_DIM;
    const unsigned short* Wg = W + (size_t)bn0 * K_DIM;

    // Per-thread A staging descriptors: 4 chunks of 8 fp32 each.
    int arow[4], acn[4];
#pragma unroll
    for (int p = 0; p < 4; ++p) {
        const int s = p * 256 + tid;
        arow[p] = s >> 3;   // 0..127
        acn[p]  = s & 7;    // chunk col 0..7
    }

    // Prologue: prefetch A tile kt=0 into registers (8 float4 = 32 VGPR).
    float4 ar[4][2];
#pragma unroll
    for (int p = 0; p < 4; ++p) {
        const float* src = Ag + (size_t)arow[p] * K_DIM + acn[p] * 8;
        ar[p][0] = *(const float4*)(src);
        ar[p][1] = *(const float4*)(src + 4);
    }

    for (int kt = 0; kt < K_DIM; kt += BK) {
        __syncthreads();  // previous compute's LDS reads done

        // B stage: 4 x global_load_lds dwordx4 (bf16 source, pre-swizzled src chunk)
#pragma unroll
        for (int p = 0; p < 4; ++p) {
            const int s     = p * 256 + wave * 64 + lane;
            const int row   = s >> 3;
            const int c     = (s & 7) ^ (row & 7);
            const int goff  = row * K_DIM + kt + c * 8;    // elems
            const int lbase = (p * 256 + wave * 64) * 8;   // elems (wave-uniform)
            __builtin_amdgcn_global_load_lds((gptr_t)(Wg + goff), (lptr_t)(Bs + lbase), 16, 0, 0);
        }

        // A stage: cvt prefetched fp32 regs -> bf16, ds_write_b128 to swizzled slot
#pragma unroll
        for (int p = 0; p < 4; ++p) {
            ushort8v o;
            o[0] = f2bf(ar[p][0].x); o[1] = f2bf(ar[p][0].y);
            o[2] = f2bf(ar[p][0].z); o[3] = f2bf(ar[p][0].w);
            o[4] = f2bf(ar[p][1].x); o[5] = f2bf(ar[p][1].y);
            o[6] = f2bf(ar[p][1].z); o[7] = f2bf(ar[p][1].w);
            const int slot = arow[p] * 8 + (acn[p] ^ (arow[p] & 7));
            *(ushort8v*)(As + slot * 8) = o;
        }

        __syncthreads();  // drains vmcnt (B in LDS) + lgkmcnt (A writes visible)

        // Issue NEXT A tile loads now: pending across the MFMA phase, drained at
        // the next iteration's first barrier -> HBM latency hidden under compute.
        if (kt + BK < K_DIM) {
#pragma unroll
            for (int p = 0; p < 4; ++p) {
                const float* src = Ag + (size_t)arow[p] * K_DIM + (kt + BK) + acn[p] * 8;
                ar[p][0] = *(const float4*)(src);
                ar[p][1] = *(const float4*)(src + 4);
            }
        }

        // Compute: 4 k-steps of K=16, 16 x mfma_f32_32x32x16_bf16
#pragma unroll
        for (int ks = 0; ks < 4; ++ks) {
            const int kc = ks * 2 + half;          // chunk index (8 elems)
            bf16x8 af[2], bfv[2];
#pragma unroll
            for (int i = 0; i < 2; ++i) {
                const int arw = wr * 64 + i * 32 + l31;
                af[i]  = *(const bf16x8*)(As + arw * 64 + (kc ^ (arw & 7)) * 8);
                const int brw = wc * 64 + i * 32 + l31;
                bfv[i] = *(const bf16x8*)(Bs + brw * 64 + (kc ^ (brw & 7)) * 8);
            }
#pragma unroll
            for (int i = 0; i < 2; ++i)
#pragma unroll
                for (int j = 0; j < 2; ++j)
                    acc[i][j] = __builtin_amdgcn_mfma_f32_32x32x16_bf16(
                        af[i], bfv[j], acc[i][j], 0, 0, 0);
        }
    }

    // Epilogue: +bias, fp32 store.
    // C/D 32x32: col = lane&31, row = (reg&3) + 8*(reg>>2) + 4*(lane>>5)  [m74/m101]
#pragma unroll
    for (int j = 0; j < 2; ++j) {
        const int col = bn0 + wc * 64 + j * 32 + l31;
        const float bj = bias[col];
#pragma unroll
        for (int i = 0; i < 2; ++i) {
            const int rbase = bm0 + wr * 64 + i * 32 + 4 * half;
#pragma unroll
            for (int reg = 0; reg < 16; ++reg) {
                const int row = rbase + (reg & 3) + 8 * (reg >> 2);
                C[(size_t)row * N_DIM + col] = acc[i][j][reg] + bj;
            }
        }
    }
}

// ---------------- fallback (fully fused, no workspace) ----------------
#define LDK 40
__global__ __launch_bounds__(256) void groupfc_fused(
    const float* __restrict__ A, const float* __restrict__ W,
    const float* __restrict__ bias, float* __restrict__ C)
{
    __shared__ unsigned short As[BM * LDK];
    __shared__ unsigned short Bs[BN * LDK];
    const int tid = threadIdx.x;
    const int bm0 = blockIdx.x * BM, bn0 = blockIdx.y * BN;
    const int wave = tid >> 6, lane = tid & 63;
    const int wr = wave >> 1, wc = wave & 1;
    const int l15 = lane & 15, quad = lane >> 4;
    typedef __attribute__((ext_vector_type(4))) float f32x4;
    f32x4 acc[4][4];
#pragma unroll
    for (int i = 0; i < 4; ++i)
#pragma unroll
        for (int j = 0; j < 4; ++j) acc[i][j] = (f32x4){0.f, 0.f, 0.f, 0.f};
    const int srow = tid >> 3, sf4 = tid & 7;
    const float* Ag = A + bm0 * K_DIM;
    const float* Wg = W + bn0 * K_DIM;
    for (int kt = 0; kt < K_DIM; kt += 32) {
        __syncthreads();
        float4 av[4], bv[4];
#pragma unroll
        for (int p = 0; p < 4; ++p) {
            const int row = p * 32 + srow;
            av[p] = *(const float4*)(Ag + row * K_DIM + kt + sf4 * 4);
            bv[p] = *(const float4*)(Wg + row * K_DIM + kt + sf4 * 4);
        }
#pragma unroll
        for (int p = 0; p < 4; ++p) {
            const int row = p * 32 + srow;
            ushort4 a16, b16;
            a16.x = f2bf(av[p].x); a16.y = f2bf(av[p].y);
            a16.z = f2bf(av[p].z); a16.w = f2bf(av[p].w);
            b16.x = f2bf(bv[p].x); b16.y = f2bf(bv[p].y);
            b16.z = f2bf(bv[p].z); b16.w = f2bf(bv[p].w);
            *(ushort4*)(&As[row * LDK + sf4 * 4]) = a16;
            *(ushort4*)(&Bs[row * LDK + sf4 * 4]) = b16;
        }
        __syncthreads();
        bf16x8 af[4], bfv[4];
#pragma unroll
        for (int i = 0; i < 4; ++i) {
            af[i]  = *(const bf16x8*)(&As[(wr * 64 + i * 16 + l15) * LDK + quad * 8]);
            bfv[i] = *(const bf16x8*)(&Bs[(wc * 64 + i * 16 + l15) * LDK + quad * 8]);
        }
#pragma unroll
        for (int i = 0; i < 4; ++i)
#pragma unroll
            for (int j = 0; j < 4; ++j)
                acc[i][j] = __builtin_amdgcn_mfma_f32_16x16x32_bf16(af[i], bfv[j], acc[i][j], 0, 0, 0);
    }
#pragma unroll
    for (int j = 0; j < 4; ++j) {
        const int col = bn0 + wc * 64 + j * 16 + l15;
        const float bj = bias[col];
#pragma unroll
        for (int i = 0; i < 4; ++i) {
            const int row0 = bm0 + wr * 64 + i * 16 + quad * 4;
#pragma unroll
            for (int r = 0; r < 4; ++r) C[(row0 + r) * N_DIM + col] = acc[i][j][r] + bj;
        }
    }
}

extern "C" void kernel_launch(void* const* d_in, const int* in_sizes, int n_in,
                              void* d_out, int out_size, void* d_ws, size_t ws_size,
                              hipStream_t stream) {
    const float* A    = (const float*)d_in[0];
    const float* W    = (const float*)d_in[1];
    const float* bias = (const float*)d_in[2];
    float* C          = (float*)d_out;

    const size_t w_elems = (size_t)N_DIM * K_DIM;
    const size_t need    = w_elems * sizeof(unsigned short);  // 2 MB

    if (ws_size >= need) {
        unsigned short* Wbf = (unsigned short*)d_ws;
        convert_f32_bf16<<<dim3(w_elems / (256 * 8)), dim3(256), 0, stream>>>(W, Wbf);
        gemm_fused<<<dim3((M_DIM / BM) * (N_DIM / BN)), dim3(256), 0, stream>>>(A, Wbf, bias, C);
    } else {
        dim3 grid(M_DIM / BM, N_DIM / BN);
        groupfc_fused<<<grid, dim3(256), 0, stream>>>(A, W, bias, C);
    }
}